// Round 4
// baseline (155.434 us; speedup 1.0000x reference)
//
#include <hip/hip_runtime.h>

#define C   64
#define H   128
#define W   128
#define HW  (H * W)
#define NB  8

using bf16x8 = __attribute__((ext_vector_type(8))) short;
using f32x4  = __attribute__((ext_vector_type(4))) float;

__device__ __forceinline__ unsigned short f2bf(float f) {
    unsigned u = __float_as_uint(f);
    return (unsigned short)((u + 0x7fffu + ((u >> 16) & 1u)) >> 16);
}

// ---------------------------------------------------------------------------
// Prep: permute weights into MFMA-friendly layouts (bf16) + permuted b2 (f32)
//   w1p[co][kk],  kk = tap*64 + k   <- w1[co][k][tap]
//   w2p[m'][k],   m' = tap*64 + c   <- w2[c*9+tap][k]
//   b2p[m']                         <- b2[c*9+tap]
// ---------------------------------------------------------------------------
__global__ __launch_bounds__(256) void prep_weights(
    const float* __restrict__ w1, const float* __restrict__ w2,
    const float* __restrict__ b2,
    unsigned short* __restrict__ w1p, unsigned short* __restrict__ w2p,
    float* __restrict__ b2p)
{
    int i = blockIdx.x * 256 + threadIdx.x;
    if (i < 36864) {
        int co = i / 576, rem = i % 576, tap = rem >> 6, k = rem & 63;
        w1p[i] = f2bf(w1[co * 576 + k * 9 + tap]);
        int mp = i >> 6, kq = i & 63, tp2 = mp >> 6, c = mp & 63;
        w2p[i] = f2bf(w2[(c * 9 + tp2) * 64 + kq]);
    }
    if (i < 576) {
        int tap = i >> 6, c = i & 63;
        b2p[i] = b2[c * 9 + tap];
    }
}

// ---------------------------------------------------------------------------
// transpose_y: y NCHW f32 -> yT[n][pix][k] bf16. Tile = 64 px x 64 ch.
// Coalesced reads (64 lanes = 64 consecutive px) and writes (wave covers
// 2 KB contiguous). LDS tile XOR-swizzled to kill transpose bank conflicts.
// Block n = bid&7 pins each image's tiles to one XCD (warm L2 for fused_dc).
// ---------------------------------------------------------------------------
__global__ __launch_bounds__(256) void transpose_y(
    const float* __restrict__ y, unsigned short* __restrict__ yT)
{
    __shared__ unsigned short tl[64 * 64];
    const int t = threadIdx.x, b = blockIdx.x;
    const int n = b & 7, tile = b >> 3;
    const int px0 = tile * 64;
    const int wv = t >> 6, l = t & 63;

    const float* src = y + (size_t)n * C * HW + px0 + l;
    #pragma unroll
    for (int i = 0; i < 8; ++i) {
        int ch = wv * 16 + i * 2;
        float v0 = src[(size_t)ch * HW];
        float v1 = src[(size_t)(ch + 1) * HW];
        unsigned pk = (unsigned)f2bf(v0) | ((unsigned)f2bf(v1) << 16);
        *(unsigned*)&tl[l * 64 + (ch ^ ((l & 7) << 3))] = pk;
    }
    __syncthreads();

    const int px = t >> 2, c0 = (t & 3) * 16;
    const int xr = (px & 7) << 3;
    uint4 w0 = *(const uint4*)&tl[px * 64 + (c0 ^ xr)];
    uint4 w1 = *(const uint4*)&tl[px * 64 + ((c0 + 8) ^ xr)];
    unsigned short* dst = yT + ((size_t)n * HW + px0 + px) * 64 + c0;
    *(uint4*)&dst[0] = w0;
    *(uint4*)&dst[8] = w1;
}

// ---------------------------------------------------------------------------
// fused_dc: one block = one image row (128 px), 4 waves x 32 px.
// Phase 1: h = conv3x3(y,w1)+b1 via implicit GEMM, A-fragments straight from
//          yT (L2), mfma(W, Y) -> lane holds 4 consecutive co -> b64 LDS
//          writes into swizzled h tile (16 KB). h never touches HBM.
// Phase 2: hA fragments from LDS (swizzle-matched b128), GEMM2 vs w2p gives
//          the per-pixel 9-tap kernel in registers, contracted immediately
//          with the f32 x neighborhood. Store f32x4.
// ---------------------------------------------------------------------------
__global__ __launch_bounds__(256) void fused_dc(
    const float* __restrict__ x,
    const unsigned short* __restrict__ yT,
    const unsigned short* __restrict__ w1p,
    const float* __restrict__ b1,
    const unsigned short* __restrict__ w2p,
    const float* __restrict__ b2p,
    float* __restrict__ out)
{
    __shared__ unsigned short h_lds[HW == 0 ? 1 : 128 * 64];  // 16 KB

    const int t = threadIdx.x, b = blockIdx.x;
    const int n = b & 7, p = b >> 3;            // image n -> XCD n (L2 reuse)
    const int wid = t >> 6, lane = t & 63;
    const int l15 = lane & 15, lhi = lane >> 4;
    const int qw = wid << 5;                    // wave's 32-px strip

    // ---------------- phase 1: h strip for this row ----------------
    {
        f32x4 acc[4][2];
        #pragma unroll
        for (int m = 0; m < 4; ++m)
            #pragma unroll
            for (int pt = 0; pt < 2; ++pt)
                acc[m][pt] = f32x4{0.f, 0.f, 0.f, 0.f};

        const unsigned short* yTn = yT + (size_t)n * HW * 64;

        #pragma unroll 2
        for (int s = 0; s < 18; ++s) {
            int tap = s >> 1;
            int trow = tap / 3;
            int dq = tap % 3 - 1;
            int k0 = (s & 1) * 32 + lhi * 8;

            int grow = p + trow - 1;
            bool rok = (unsigned)grow < (unsigned)H;
            int cg = rok ? grow : 0;

            bf16x8 Y[2];
            #pragma unroll
            for (int pt = 0; pt < 2; ++pt) {
                int col = qw + pt * 16 + l15 + dq;
                bool ok = rok && ((unsigned)col < (unsigned)W);
                int cc = col < 0 ? 0 : (col > 127 ? 127 : col);
                bf16x8 v = *(const bf16x8*)&yTn[((size_t)cg * W + cc) * 64 + k0];
                Y[pt] = ok ? v : (bf16x8)0;
            }
            int kk = s * 32 + lhi * 8;
            bf16x8 Wf[4];
            #pragma unroll
            for (int m = 0; m < 4; ++m)
                Wf[m] = *(const bf16x8*)&w1p[(m * 16 + l15) * 576 + kk];

            #pragma unroll
            for (int m = 0; m < 4; ++m)
                #pragma unroll
                for (int pt = 0; pt < 2; ++pt)
                    acc[m][pt] = __builtin_amdgcn_mfma_f32_16x16x32_bf16(
                        Wf[m], Y[pt], acc[m][pt], 0, 0, 0);
        }

        // +b1, pack to bf16, swizzled LDS write: h[px][co..co+3]
        #pragma unroll
        for (int m = 0; m < 4; ++m) {
            float4 bq = *(const float4*)&b1[m * 16 + lhi * 4];
            #pragma unroll
            for (int pt = 0; pt < 2; ++pt) {
                int px = qw + pt * 16 + l15;
                int cb = m * 16 + lhi * 4;
                unsigned lo = (unsigned)f2bf(acc[m][pt][0] + bq.x)
                            | ((unsigned)f2bf(acc[m][pt][1] + bq.y) << 16);
                unsigned hi = (unsigned)f2bf(acc[m][pt][2] + bq.z)
                            | ((unsigned)f2bf(acc[m][pt][3] + bq.w) << 16);
                uint2 pk; pk.x = lo; pk.y = hi;
                *(uint2*)&h_lds[px * 64 + (cb ^ ((px & 7) << 3))] = pk;
            }
        }
    }
    __syncthreads();

    // ---------------- phase 2: dynamic conv ----------------
    bf16x8 hA[2][2];
    #pragma unroll
    for (int pt = 0; pt < 2; ++pt)
        #pragma unroll
        for (int ks = 0; ks < 2; ++ks) {
            int px = qw + pt * 16 + l15;
            int ko = ks * 32 + lhi * 8;
            hA[pt][ks] = *(const bf16x8*)&h_lds[px * 64 + (ko ^ ((px & 7) << 3))];
        }

    for (int cc = 0; cc < 4; ++cc) {
        const int c = cc * 16 + l15;
        const float* xc = x + ((size_t)n * C + c) * HW;

        #pragma unroll
        for (int pt = 0; pt < 2; ++pt) {
            const int cb = qw + pt * 16 + lhi * 4;   // 16B-aligned col base
            float xn[3][6];
            #pragma unroll
            for (int ri = 0; ri < 3; ++ri) {
                int grow = p - 1 + ri;               // wave-uniform
                if ((unsigned)grow < (unsigned)H) {
                    const float* xr = xc + (size_t)grow * W;
                    float4 mid = *(const float4*)&xr[cb];
                    xn[ri][1] = mid.x; xn[ri][2] = mid.y;
                    xn[ri][3] = mid.z; xn[ri][4] = mid.w;
                    xn[ri][0] = (cb > 0)   ? xr[cb - 1] : 0.f;
                    xn[ri][5] = (cb < 124) ? xr[cb + 4] : 0.f;
                } else {
                    #pragma unroll
                    for (int cj = 0; cj < 6; ++cj) xn[ri][cj] = 0.f;
                }
            }

            f32x4 oacc = {0.f, 0.f, 0.f, 0.f};
            #pragma unroll
            for (int tap = 0; tap < 9; ++tap) {
                const int mrow = tap * 64 + cc * 16 + l15;
                bf16x8 w2f0 = *(const bf16x8*)&w2p[mrow * 64 + lhi * 8];
                bf16x8 w2f1 = *(const bf16x8*)&w2p[mrow * 64 + 32 + lhi * 8];
                float bv = b2p[mrow];
                f32x4 kf = {bv, bv, bv, bv};
                kf = __builtin_amdgcn_mfma_f32_16x16x32_bf16(hA[pt][0], w2f0, kf, 0, 0, 0);
                kf = __builtin_amdgcn_mfma_f32_16x16x32_bf16(hA[pt][1], w2f1, kf, 0, 0, 0);
                int ri = tap / 3, cj = tap % 3;
                #pragma unroll
                for (int r = 0; r < 4; ++r)
                    oacc[r] = fmaf(kf[r], xn[ri][r + cj], oacc[r]);
            }

            float* dst = out + ((size_t)n * C + c) * HW + (size_t)p * W + cb;
            *(f32x4*)dst = oacc;
        }
    }
}

extern "C" void kernel_launch(void* const* d_in, const int* in_sizes, int n_in,
                              void* d_out, int out_size, void* d_ws, size_t ws_size,
                              hipStream_t stream)
{
    const float* x  = (const float*)d_in[0];
    const float* y  = (const float*)d_in[1];
    const float* w1 = (const float*)d_in[2];
    const float* b1 = (const float*)d_in[3];
    const float* w2 = (const float*)d_in[4];
    const float* b2 = (const float*)d_in[5];
    float* out = (float*)d_out;

    char* ws = (char*)d_ws;
    unsigned short* yT  = (unsigned short*)ws;                       // 16,777,216 B
    unsigned short* w1p = (unsigned short*)(ws + 16777216);          // 73,728 B
    unsigned short* w2p = (unsigned short*)(ws + 16777216 + 73728);  // 73,728 B
    float*          b2p = (float*)(ws + 16777216 + 147456);          // 2,304 B

    prep_weights<<<144, 256, 0, stream>>>(w1, w2, b2, w1p, w2p, b2p);
    transpose_y<<<NB * HW / 64, 256, 0, stream>>>(y, yT);
    fused_dc<<<NB * H, 256, 0, stream>>>(x, yT, w1p, b1, w2p, b2p, out);
}

// Round 5
// 148.571 us; speedup vs baseline: 1.0462x; 1.0462x over previous
//
#include <hip/hip_runtime.h>

#define C   64
#define H   128
#define W   128
#define HW  (H * W)
#define NB  8

using bf16x8 = __attribute__((ext_vector_type(8))) short;
using f32x4  = __attribute__((ext_vector_type(4))) float;

__device__ __forceinline__ unsigned short f2bf(float f) {
    unsigned u = __float_as_uint(f);
    return (unsigned short)((u + 0x7fffu + ((u >> 16) & 1u)) >> 16);
}

// ---------------------------------------------------------------------------
// Prep: permute weights into MFMA-friendly layouts (bf16) + permuted b2 (f32)
// ---------------------------------------------------------------------------
__global__ __launch_bounds__(256) void prep_weights(
    const float* __restrict__ w1, const float* __restrict__ w2,
    const float* __restrict__ b2,
    unsigned short* __restrict__ w1p, unsigned short* __restrict__ w2p,
    float* __restrict__ b2p)
{
    int i = blockIdx.x * 256 + threadIdx.x;
    if (i < 36864) {
        int co = i / 576, rem = i % 576, tap = rem >> 6, k = rem & 63;
        w1p[i] = f2bf(w1[co * 576 + k * 9 + tap]);
        int mp = i >> 6, kq = i & 63, tp2 = mp >> 6, c = mp & 63;
        w2p[i] = f2bf(w2[(c * 9 + tp2) * 64 + kq]);
    }
    if (i < 576) {
        int tap = i >> 6, c = i & 63;
        b2p[i] = b2[c * 9 + tap];
    }
}

// ---------------------------------------------------------------------------
// transpose_y: y NCHW f32 -> yT[n][pix][k] bf16 (LDS-tiled, XOR-swizzled)
// ---------------------------------------------------------------------------
__global__ __launch_bounds__(256) void transpose_y(
    const float* __restrict__ y, unsigned short* __restrict__ yT)
{
    __shared__ unsigned short tl[64 * 64];
    const int t = threadIdx.x, b = blockIdx.x;
    const int n = b & 7, tile = b >> 3;
    const int px0 = tile * 64;
    const int wv = t >> 6, l = t & 63;

    const float* src = y + (size_t)n * C * HW + px0 + l;
    #pragma unroll
    for (int i = 0; i < 8; ++i) {
        int ch = wv * 16 + i * 2;
        float v0 = src[(size_t)ch * HW];
        float v1 = src[(size_t)(ch + 1) * HW];
        unsigned pk = (unsigned)f2bf(v0) | ((unsigned)f2bf(v1) << 16);
        *(unsigned*)&tl[l * 64 + (ch ^ ((l & 7) << 3))] = pk;
    }
    __syncthreads();

    const int px = t >> 2, c0 = (t & 3) * 16;
    const int xr = (px & 7) << 3;
    uint4 w0 = *(const uint4*)&tl[px * 64 + (c0 ^ xr)];
    uint4 w1 = *(const uint4*)&tl[px * 64 + ((c0 + 8) ^ xr)];
    unsigned short* dst = yT + ((size_t)n * HW + px0 + px) * 64 + c0;
    *(uint4*)&dst[0] = w0;
    *(uint4*)&dst[8] = w1;
}

// ---------------------------------------------------------------------------
// fused_dc: one block = one image row, 4 waves x 32 px, NO inter-phase
// barrier (each wave reads back only the h_lds strip it wrote).
// Phase 1: h = conv3x3(y,w1)+b1, implicit GEMM, 2-deep software pipeline.
// Phase 2: GEMM2 (per-pixel 9-tap kernel) + x contraction, w2 prefetched
// 1 tap ahead, x issued before the hA LDS readback.
// ---------------------------------------------------------------------------
__global__ __launch_bounds__(256, 4) void fused_dc(
    const float* __restrict__ x,
    const unsigned short* __restrict__ yT,
    const unsigned short* __restrict__ w1p,
    const float* __restrict__ b1,
    const unsigned short* __restrict__ w2p,
    const float* __restrict__ b2p,
    float* __restrict__ out)
{
    __shared__ unsigned short h_lds[128 * 64];  // 16 KB

    const int t = threadIdx.x, b = blockIdx.x;
    const int n = b & 7, p = b >> 3;            // image n -> XCD n (L2 reuse)
    const int wid = t >> 6, lane = t & 63;
    const int l15 = lane & 15, lhi = lane >> 4;
    const int qw = wid << 5;                    // wave's 32-px strip

    const unsigned short* yTn = yT + (size_t)n * HW * 64;

    // ---------------- phase 1: h strip (software-pipelined) ----------------
    f32x4 acc[4][2];
    #pragma unroll
    for (int m = 0; m < 4; ++m)
        #pragma unroll
        for (int pt = 0; pt < 2; ++pt)
            acc[m][pt] = f32x4{0.f, 0.f, 0.f, 0.f};

    auto loadS = [&](int s, bf16x8 (&Y)[2], bf16x8 (&Wf)[4]) {
        const int tap = s >> 1, trow = tap / 3, dq = tap % 3 - 1;
        const int k0 = (s & 1) * 32 + lhi * 8;
        const int grow = p + trow - 1;
        const bool rok = (unsigned)grow < (unsigned)H;
        const int cg = rok ? grow : 0;
        #pragma unroll
        for (int pt = 0; pt < 2; ++pt) {
            int col = qw + pt * 16 + l15 + dq;
            bool ok = rok && ((unsigned)col < (unsigned)W);
            int cl = col < 0 ? 0 : (col > 127 ? 127 : col);
            bf16x8 v = *(const bf16x8*)&yTn[((size_t)cg * W + cl) * 64 + k0];
            Y[pt] = ok ? v : (bf16x8)0;
        }
        const int kk = s * 32 + lhi * 8;
        #pragma unroll
        for (int m = 0; m < 4; ++m)
            Wf[m] = *(const bf16x8*)&w1p[(m * 16 + l15) * 576 + kk];
    };
    auto mfmaS = [&](bf16x8 (&Y)[2], bf16x8 (&Wf)[4]) {
        #pragma unroll
        for (int m = 0; m < 4; ++m)
            #pragma unroll
            for (int pt = 0; pt < 2; ++pt)
                acc[m][pt] = __builtin_amdgcn_mfma_f32_16x16x32_bf16(
                    Wf[m], Y[pt], acc[m][pt], 0, 0, 0);
    };

    {
        bf16x8 Ya[2], Wa[4], Yb[2], Wb[4];
        loadS(0, Ya, Wa);
        #pragma unroll
        for (int s = 0; s < 18; s += 2) {
            loadS(s + 1, Yb, Wb);          // prefetch odd stage
            mfmaS(Ya, Wa);
            if (s + 2 < 18) loadS(s + 2, Ya, Wa);  // prefetch next even stage
            mfmaS(Yb, Wb);
        }
    }

    // +b1, pack bf16, swizzled LDS write: h[px][co..co+3]
    #pragma unroll
    for (int m = 0; m < 4; ++m) {
        float4 bq = *(const float4*)&b1[m * 16 + lhi * 4];
        #pragma unroll
        for (int pt = 0; pt < 2; ++pt) {
            int px = qw + pt * 16 + l15;
            int cb = m * 16 + lhi * 4;
            unsigned lo = (unsigned)f2bf(acc[m][pt][0] + bq.x)
                        | ((unsigned)f2bf(acc[m][pt][1] + bq.y) << 16);
            unsigned hi = (unsigned)f2bf(acc[m][pt][2] + bq.z)
                        | ((unsigned)f2bf(acc[m][pt][3] + bq.w) << 16);
            uint2 pk; pk.x = lo; pk.y = hi;
            *(uint2*)&h_lds[px * 64 + (cb ^ ((px & 7) << 3))] = pk;
        }
    }
    // NO __syncthreads(): each wave reads back only its own strip; same-wave
    // LDS write->read ordering is handled by lgkmcnt. Waves stagger freely.

    // ---------------- phase 2: dynamic conv ----------------
    auto loadX = [&](int cc, float (&xn)[2][3][6]) {
        const int c = cc * 16 + l15;
        const float* xc = x + ((size_t)n * C + c) * HW;
        #pragma unroll
        for (int pt = 0; pt < 2; ++pt) {
            const int cb = qw + pt * 16 + lhi * 4;
            #pragma unroll
            for (int ri = 0; ri < 3; ++ri) {
                int grow = p - 1 + ri;               // wave-uniform
                if ((unsigned)grow < (unsigned)H) {
                    const float* xr = xc + (size_t)grow * W;
                    float4 mid = *(const float4*)&xr[cb];
                    xn[pt][ri][1] = mid.x; xn[pt][ri][2] = mid.y;
                    xn[pt][ri][3] = mid.z; xn[pt][ri][4] = mid.w;
                    xn[pt][ri][0] = (cb > 0)   ? xr[cb - 1] : 0.f;
                    xn[pt][ri][5] = (cb < 124) ? xr[cb + 4] : 0.f;
                } else {
                    #pragma unroll
                    for (int cj = 0; cj < 6; ++cj) xn[pt][ri][cj] = 0.f;
                }
            }
        }
    };

    // issue x loads for cc=0 before the hA readback (hide global latency
    // under the LDS round-trip)
    float xn[2][3][6];
    loadX(0, xn);

    bf16x8 hA[2][2];
    #pragma unroll
    for (int pt = 0; pt < 2; ++pt)
        #pragma unroll
        for (int ks = 0; ks < 2; ++ks) {
            int px = qw + pt * 16 + l15;
            int ko = ks * 32 + lhi * 8;
            hA[pt][ks] = *(const bf16x8*)&h_lds[px * 64 + (ko ^ ((px & 7) << 3))];
        }

    #pragma unroll
    for (int cc = 0; cc < 4; ++cc) {
        const int c = cc * 16 + l15;

        bf16x8 wf0[2], wf1[2];
        float  bv[2];
        auto loadW2 = [&](int tap, int bi) {
            const int mrow = tap * 64 + cc * 16 + l15;
            wf0[bi] = *(const bf16x8*)&w2p[mrow * 64 + lhi * 8];
            wf1[bi] = *(const bf16x8*)&w2p[mrow * 64 + 32 + lhi * 8];
            bv[bi]  = b2p[mrow];
        };

        f32x4 oacc[2];
        oacc[0] = f32x4{0.f, 0.f, 0.f, 0.f};
        oacc[1] = f32x4{0.f, 0.f, 0.f, 0.f};

        loadW2(0, 0);
        #pragma unroll
        for (int tap = 0; tap < 9; ++tap) {
            if (tap < 8) loadW2(tap + 1, (tap + 1) & 1);
            const int bi = tap & 1;
            const int ri = tap / 3, cj = tap % 3;
            #pragma unroll
            for (int pt = 0; pt < 2; ++pt) {
                f32x4 kf = {bv[bi], bv[bi], bv[bi], bv[bi]};
                kf = __builtin_amdgcn_mfma_f32_16x16x32_bf16(hA[pt][0], wf0[bi], kf, 0, 0, 0);
                kf = __builtin_amdgcn_mfma_f32_16x16x32_bf16(hA[pt][1], wf1[bi], kf, 0, 0, 0);
                #pragma unroll
                for (int r = 0; r < 4; ++r)
                    oacc[pt][r] = fmaf(kf[r], xn[pt][ri][r + cj], oacc[pt][r]);
            }
        }

        // store, then fetch next cc's x (overlaps with next cc's first taps)
        #pragma unroll
        for (int pt = 0; pt < 2; ++pt) {
            int cb = qw + pt * 16 + lhi * 4;
            float* dst = out + ((size_t)n * C + c) * HW + (size_t)p * W + cb;
            *(f32x4*)dst = oacc[pt];
        }
        if (cc < 3) loadX(cc + 1, xn);
    }
}

extern "C" void kernel_launch(void* const* d_in, const int* in_sizes, int n_in,
                              void* d_out, int out_size, void* d_ws, size_t ws_size,
                              hipStream_t stream)
{
    const float* x  = (const float*)d_in[0];
    const float* y  = (const float*)d_in[1];
    const float* w1 = (const float*)d_in[2];
    const float* b1 = (const float*)d_in[3];
    const float* w2 = (const float*)d_in[4];
    const float* b2 = (const float*)d_in[5];
    float* out = (float*)d_out;

    char* ws = (char*)d_ws;
    unsigned short* yT  = (unsigned short*)ws;                       // 16,777,216 B
    unsigned short* w1p = (unsigned short*)(ws + 16777216);          // 73,728 B
    unsigned short* w2p = (unsigned short*)(ws + 16777216 + 73728);  // 73,728 B
    float*          b2p = (float*)(ws + 16777216 + 147456);          // 2,304 B

    prep_weights<<<144, 256, 0, stream>>>(w1, w2, b2, w1p, w2p, b2p);
    transpose_y<<<NB * HW / 64, 256, 0, stream>>>(y, yT);
    fused_dc<<<NB * H, 256, 0, stream>>>(x, yT, w1p, b1, w2p, b2p, out);
}

// Round 6
// 84.523 us; speedup vs baseline: 1.8389x; 1.7577x over previous
//
#include <hip/hip_runtime.h>

#define C   64
#define H   128
#define W   128
#define HW  (H * W)
#define NB  8

using bf16x8 = __attribute__((ext_vector_type(8))) short;
using f32x4  = __attribute__((ext_vector_type(4))) float;

__device__ __forceinline__ unsigned short f2bf(float f) {
    unsigned u = __float_as_uint(f);
    return (unsigned short)((u + 0x7fffu + ((u >> 16) & 1u)) >> 16);
}

// ---------------------------------------------------------------------------
// Prep: emit PER-LANE MFMA fragments so every weight load in fused_dc is a
// coalesced 16B/lane b128 read.
//   w1f[((s*4+m)*64+lane)*8+j]      : A-frag of w1 for stage s, m-tile m
//       = w1[co=m*16+l15][k][tap],  kk=s*32+lhi*8+j, tap=kk>>6, k=kk&63
//   w2f[(((cc*9+tap)*2+ks)*64+lane)*8+j] : A-frag of w2 (GEMM2)
//       = w2[(c'*9+tap)*64 + k],    c'=cc*16+l15, k=ks*32+lhi*8+j
//   b2f[((cc*9+tap)*64+lane)*4+r]   : per-lane bias matching D-row map
//       = b2[(cc*16+lhi*4+r)*9+tap]
// ---------------------------------------------------------------------------
__global__ __launch_bounds__(256) void prep_weights(
    const float* __restrict__ w1, const float* __restrict__ w2,
    const float* __restrict__ b2,
    unsigned short* __restrict__ w1f, unsigned short* __restrict__ w2f,
    float* __restrict__ b2f)
{
    int i = blockIdx.x * 256 + threadIdx.x;   // 0..36863
    if (i < 36864) {
        {   // w1f
            int j = i & 7, lane = (i >> 3) & 63, m = (i >> 9) & 3, s = i >> 11;
            int l15 = lane & 15, lhi = lane >> 4;
            int co = m * 16 + l15;
            int kk = s * 32 + lhi * 8 + j;
            int tap = kk >> 6, k = kk & 63;
            w1f[i] = f2bf(w1[co * 576 + k * 9 + tap]);
        }
        {   // w2f
            int j = i & 7, lane = (i >> 3) & 63, ks = (i >> 9) & 1, t9 = i >> 10;
            int tap = t9 % 9, cc = t9 / 9;
            int cp = cc * 16 + (lane & 15);
            int k = ks * 32 + (lane >> 4) * 8 + j;
            w2f[i] = f2bf(w2[(cp * 9 + tap) * 64 + k]);
        }
    }
    if (i < 9216) {  // b2f
        int r = i & 3, lane = (i >> 2) & 63, t9 = i >> 8;
        int tap = t9 % 9, cc = t9 / 9;
        int cpp = cc * 16 + ((lane >> 4) << 2) + r;
        b2f[i] = b2[cpp * 9 + tap];
    }
}

// ---------------------------------------------------------------------------
// transpose_y: y NCHW f32 -> yT[n][pix][k] bf16 (LDS-tiled, XOR-swizzled)
// ---------------------------------------------------------------------------
__global__ __launch_bounds__(256) void transpose_y(
    const float* __restrict__ y, unsigned short* __restrict__ yT)
{
    __shared__ unsigned short tl[64 * 64];
    const int t = threadIdx.x, b = blockIdx.x;
    const int n = b & 7, tile = b >> 3;
    const int px0 = tile * 64;
    const int wv = t >> 6, l = t & 63;

    const float* src = y + (size_t)n * C * HW + px0 + l;
    #pragma unroll
    for (int i = 0; i < 8; ++i) {
        int ch = wv * 16 + i * 2;
        float v0 = src[(size_t)ch * HW];
        float v1 = src[(size_t)(ch + 1) * HW];
        unsigned pk = (unsigned)f2bf(v0) | ((unsigned)f2bf(v1) << 16);
        *(unsigned*)&tl[l * 64 + (ch ^ ((l & 7) << 3))] = pk;
    }
    __syncthreads();

    const int px = t >> 2, c0 = (t & 3) * 16;
    const int xr = (px & 7) << 3;
    uint4 w0 = *(const uint4*)&tl[px * 64 + (c0 ^ xr)];
    uint4 w1 = *(const uint4*)&tl[px * 64 + ((c0 + 8) ^ xr)];
    unsigned short* dst = yT + ((size_t)n * HW + px0 + px) * 64 + c0;
    *(uint4*)&dst[0] = w0;
    *(uint4*)&dst[8] = w1;
}

// ---------------------------------------------------------------------------
// fused_dc: one block = one image row, 4 waves x 32 px, no inter-phase
// barrier (each wave reads back only the h_lds strip it wrote).
// Phase 1: h = conv3x3(y,w1)+b1, implicit GEMM, D=[co][pix] (mfma(W,Y)).
// Phase 2: kf = mfma(w2frag, hfrag) -> D=[channel][PIXEL]: lane l15 = pixel,
//          so x loads and out stores are lane-contiguous (4 lines/instr,
//          not 64). Weights/bias come pre-fragmented (coalesced b128).
// ---------------------------------------------------------------------------
__global__ __launch_bounds__(256, 4) void fused_dc(
    const float* __restrict__ x,
    const unsigned short* __restrict__ yT,
    const unsigned short* __restrict__ w1f,
    const float* __restrict__ b1,
    const unsigned short* __restrict__ w2f,
    const float* __restrict__ b2f,
    float* __restrict__ out)
{
    __shared__ unsigned short h_lds[128 * 64];  // 16 KB

    const int t = threadIdx.x, b = blockIdx.x;
    const int n = b & 7, p = b >> 3;            // image n -> XCD n (L2 reuse)
    const int wid = t >> 6, lane = t & 63;
    const int l15 = lane & 15, lhi = lane >> 4;
    const int qw = wid << 5;                    // wave's 32-px strip

    const unsigned short* yTn = yT + (size_t)n * HW * 64;

    // ---------------- phase 1: h strip ----------------
    {
        f32x4 acc[4][2];
        #pragma unroll
        for (int m = 0; m < 4; ++m)
            #pragma unroll
            for (int pt = 0; pt < 2; ++pt)
                acc[m][pt] = f32x4{0.f, 0.f, 0.f, 0.f};

        #pragma unroll
        for (int s = 0; s < 18; ++s) {
            const int tap = s >> 1, trow = tap / 3, dq = tap % 3 - 1;
            const int k0 = (s & 1) * 32 + lhi * 8;
            const int grow = p + trow - 1;
            const bool rok = (unsigned)grow < (unsigned)H;
            const int cg = rok ? grow : 0;

            bf16x8 Y[2];
            #pragma unroll
            for (int pt = 0; pt < 2; ++pt) {
                int col = qw + pt * 16 + l15 + dq;
                bool ok = rok && ((unsigned)col < (unsigned)W);
                int cl = col < 0 ? 0 : (col > 127 ? 127 : col);
                bf16x8 v = *(const bf16x8*)&yTn[((size_t)cg * W + cl) * 64 + k0];
                Y[pt] = ok ? v : (bf16x8)0;
            }
            bf16x8 Wf[4];
            #pragma unroll
            for (int m = 0; m < 4; ++m)
                Wf[m] = *(const bf16x8*)&w1f[(size_t)((s * 4 + m) * 64 + lane) * 8];

            #pragma unroll
            for (int m = 0; m < 4; ++m)
                #pragma unroll
                for (int pt = 0; pt < 2; ++pt)
                    acc[m][pt] = __builtin_amdgcn_mfma_f32_16x16x32_bf16(
                        Wf[m], Y[pt], acc[m][pt], 0, 0, 0);
        }

        // +b1, pack bf16, swizzled LDS write: h[px][co..co+3]
        #pragma unroll
        for (int m = 0; m < 4; ++m) {
            float4 bq = *(const float4*)&b1[m * 16 + lhi * 4];
            #pragma unroll
            for (int pt = 0; pt < 2; ++pt) {
                int px = qw + pt * 16 + l15;
                int cb = m * 16 + lhi * 4;
                unsigned lo = (unsigned)f2bf(acc[m][pt][0] + bq.x)
                            | ((unsigned)f2bf(acc[m][pt][1] + bq.y) << 16);
                unsigned hi = (unsigned)f2bf(acc[m][pt][2] + bq.z)
                            | ((unsigned)f2bf(acc[m][pt][3] + bq.w) << 16);
                uint2 pk; pk.x = lo; pk.y = hi;
                *(uint2*)&h_lds[px * 64 + (cb ^ ((px & 7) << 3))] = pk;
            }
        }
    }
    // No __syncthreads(): each wave reads back only its own strip.

    // ---------------- phase 2: dynamic conv ----------------
    bf16x8 hA[2][2];   // B-operand fragments: lane=pixel(l15), k=lhi*8
    #pragma unroll
    for (int pt = 0; pt < 2; ++pt)
        #pragma unroll
        for (int ks = 0; ks < 2; ++ks) {
            int px = qw + pt * 16 + l15;
            int ko = ks * 32 + lhi * 8;
            hA[pt][ks] = *(const bf16x8*)&h_lds[px * 64 + (ko ^ ((px & 7) << 3))];
        }

    const float* xn_ = x + (size_t)n * C * HW;
    float* out_ = out + (size_t)n * C * HW;

    #pragma unroll
    for (int cc = 0; cc < 4; ++cc) {
        bf16x8 wA0[2], wA1[2];
        f32x4  bq[2];
        float  xv[2][2][4];   // [buf][pt][r]

        auto loadTap = [&](int tap, int bi) {
            const int t9 = cc * 9 + tap;
            wA0[bi] = *(const bf16x8*)&w2f[(size_t)((t9 * 2 + 0) * 64 + lane) * 8];
            wA1[bi] = *(const bf16x8*)&w2f[(size_t)((t9 * 2 + 1) * 64 + lane) * 8];
            bq[bi]  = *(const f32x4*)&b2f[(size_t)(t9 * 64 + lane) * 4];
            const int ri = tap / 3, cj = tap % 3;
            const int grow = p + ri - 1;                    // wave-uniform
            const bool rok = (unsigned)grow < (unsigned)H;
            const int cr = rok ? grow : 0;
            #pragma unroll
            for (int pt = 0; pt < 2; ++pt) {
                int col = qw + pt * 16 + l15 + cj - 1;
                bool ok = rok && ((unsigned)col < (unsigned)W);
                int cl = col < 0 ? 0 : (col > 127 ? 127 : col);
                const float* xb = xn_ + (size_t)(cc * 16 + lhi * 4) * HW
                                + (size_t)cr * W + cl;
                #pragma unroll
                for (int r = 0; r < 4; ++r) {
                    float v = xb[(size_t)r * HW];
                    xv[bi][pt][r] = ok ? v : 0.f;
                }
            }
        };

        f32x4 oacc[2];
        oacc[0] = f32x4{0.f, 0.f, 0.f, 0.f};
        oacc[1] = f32x4{0.f, 0.f, 0.f, 0.f};

        loadTap(0, 0);
        #pragma unroll
        for (int tap = 0; tap < 9; ++tap) {
            if (tap < 8) loadTap(tap + 1, (tap + 1) & 1);
            const int bi = tap & 1;
            #pragma unroll
            for (int pt = 0; pt < 2; ++pt) {
                f32x4 kf = __builtin_amdgcn_mfma_f32_16x16x32_bf16(
                    wA0[bi], hA[pt][0], bq[bi], 0, 0, 0);
                kf = __builtin_amdgcn_mfma_f32_16x16x32_bf16(
                    wA1[bi], hA[pt][1], kf, 0, 0, 0);
                #pragma unroll
                for (int r = 0; r < 4; ++r)
                    oacc[pt][r] = fmaf(kf[r], xv[bi][pt][r], oacc[pt][r]);
            }
        }

        // coalesced scalar stores: lane l15 = consecutive pixels
        #pragma unroll
        for (int pt = 0; pt < 2; ++pt)
            #pragma unroll
            for (int r = 0; r < 4; ++r)
                out_[(size_t)(cc * 16 + lhi * 4 + r) * HW
                     + (size_t)p * W + qw + pt * 16 + l15] = oacc[pt][r];
    }
}

extern "C" void kernel_launch(void* const* d_in, const int* in_sizes, int n_in,
                              void* d_out, int out_size, void* d_ws, size_t ws_size,
                              hipStream_t stream)
{
    const float* x  = (const float*)d_in[0];
    const float* y  = (const float*)d_in[1];
    const float* w1 = (const float*)d_in[2];
    const float* b1 = (const float*)d_in[3];
    const float* w2 = (const float*)d_in[4];
    const float* b2 = (const float*)d_in[5];
    float* out = (float*)d_out;

    char* ws = (char*)d_ws;
    unsigned short* yT  = (unsigned short*)ws;                        // 16,777,216 B
    unsigned short* w1f = (unsigned short*)(ws + 16777216);           // 73,728 B
    unsigned short* w2f = (unsigned short*)(ws + 16777216 + 73728);   // 73,728 B
    float*          b2f = (float*)(ws + 16777216 + 147456);           // 36,864 B

    prep_weights<<<144, 256, 0, stream>>>(w1, w2, b2, w1f, w2f, b2f);
    transpose_y<<<NB * HW / 64, 256, 0, stream>>>(y, yT);
    fused_dc<<<NB * H, 256, 0, stream>>>(x, yT, w1f, b1, w2f, b2f, out);
}

// Round 7
// 66.511 us; speedup vs baseline: 2.3370x; 1.2708x over previous
//
#include <hip/hip_runtime.h>

#define C   64
#define H   128
#define W   128
#define HW  (H * W)
#define NB  8

using bf16x8 = __attribute__((ext_vector_type(8))) short;
using f32x4  = __attribute__((ext_vector_type(4))) float;

__device__ __forceinline__ unsigned short f2bf(float f) {
    unsigned u = __float_as_uint(f);
    return (unsigned short)((u + 0x7fffu + ((u >> 16) & 1u)) >> 16);
}

// ---------------------------------------------------------------------------
// Prep: per-lane MFMA fragment tables (unchanged layouts from round 6).
//   w1f[((s*4+m)*64+lane)*8+j], w2f[(((cc*9+tap)*2+ks)*64+lane)*8+j],
//   b2f[((cc*9+tap)*64+lane)*4+r]
// ---------------------------------------------------------------------------
__global__ __launch_bounds__(256) void prep_weights(
    const float* __restrict__ w1, const float* __restrict__ w2,
    const float* __restrict__ b2,
    unsigned short* __restrict__ w1f, unsigned short* __restrict__ w2f,
    float* __restrict__ b2f)
{
    int i = blockIdx.x * 256 + threadIdx.x;   // 0..36863
    if (i < 36864) {
        {   // w1f
            int j = i & 7, lane = (i >> 3) & 63, m = (i >> 9) & 3, s = i >> 11;
            int l15 = lane & 15, lhi = lane >> 4;
            int co = m * 16 + l15;
            int kk = s * 32 + lhi * 8 + j;
            int tap = kk >> 6, k = kk & 63;
            w1f[i] = f2bf(w1[co * 576 + k * 9 + tap]);
        }
        {   // w2f
            int j = i & 7, lane = (i >> 3) & 63, ks = (i >> 9) & 1, t9 = i >> 10;
            int tap = t9 % 9, cc = t9 / 9;
            int cp = cc * 16 + (lane & 15);
            int k = ks * 32 + (lane >> 4) * 8 + j;
            w2f[i] = f2bf(w2[(cp * 9 + tap) * 64 + k]);
        }
    }
    if (i < 9216) {  // b2f
        int r = i & 3, lane = (i >> 2) & 63, t9 = i >> 8;
        int tap = t9 % 9, cc = t9 / 9;
        int cpp = cc * 16 + ((lane >> 4) << 2) + r;
        b2f[i] = b2[cpp * 9 + tap];
    }
}

// ---------------------------------------------------------------------------
// transpose_y: y NCHW f32 -> yT[n][pix][k] bf16 (LDS-tiled, XOR-swizzled)
// ---------------------------------------------------------------------------
__global__ __launch_bounds__(256) void transpose_y(
    const float* __restrict__ y, unsigned short* __restrict__ yT)
{
    __shared__ unsigned short tl[64 * 64];
    const int t = threadIdx.x, b = blockIdx.x;
    const int n = b & 7, tile = b >> 3;
    const int px0 = tile * 64;
    const int wv = t >> 6, l = t & 63;

    const float* src = y + (size_t)n * C * HW + px0 + l;
    #pragma unroll
    for (int i = 0; i < 8; ++i) {
        int ch = wv * 16 + i * 2;
        float v0 = src[(size_t)ch * HW];
        float v1 = src[(size_t)(ch + 1) * HW];
        unsigned pk = (unsigned)f2bf(v0) | ((unsigned)f2bf(v1) << 16);
        *(unsigned*)&tl[l * 64 + (ch ^ ((l & 7) << 3))] = pk;
    }
    __syncthreads();

    const int px = t >> 2, c0 = (t & 3) * 16;
    const int xr = (px & 7) << 3;
    uint4 w0 = *(const uint4*)&tl[px * 64 + (c0 ^ xr)];
    uint4 w1 = *(const uint4*)&tl[px * 64 + ((c0 + 8) ^ xr)];
    unsigned short* dst = yT + ((size_t)n * HW + px0 + px) * 64 + c0;
    *(uint4*)&dst[0] = w0;
    *(uint4*)&dst[8] = w1;
}

// ---------------------------------------------------------------------------
// fused_dc: block = 4 waves x 4 image rows; each wave owns ONE full 128-px
// row (pt = 8 tiles of 16 px). Per weight-fragment read -> 8 MFMAs (was 2):
// 4x less per-CU weight streaming. Grid = 256 blocks = 1 per CU.
// Phase 1: h = conv3x3(y,w1)+b1 implicit GEMM, D=[co][pix], acc[4][8].
// Phase 2: kf = mfma(w2frag, hfrag) per tap, contracted with f32 x, lane=px
// coalesced. h handoff via per-wave private 16 KB h_lds strip (no barrier).
// ---------------------------------------------------------------------------
__global__ __launch_bounds__(256, 1) void fused_dc(
    const float* __restrict__ x,
    const unsigned short* __restrict__ yT,
    const unsigned short* __restrict__ w1f,
    const float* __restrict__ b1,
    const unsigned short* __restrict__ w2f,
    const float* __restrict__ b2f,
    float* __restrict__ out)
{
    __shared__ unsigned short h_lds[4 * 128 * 64];  // 64 KB, 16 KB per wave

    const int t = threadIdx.x, b = blockIdx.x;
    const int n = b & 7;                       // image n -> XCD n (L2 reuse)
    const int wid = t >> 6, lane = t & 63;
    const int l15 = lane & 15, lhi = lane >> 4;
    const int p = ((b >> 3) << 2) + wid;       // this wave's image row

    const unsigned short* yTn = yT + (size_t)n * HW * 64;
    unsigned short* h_my = &h_lds[wid * 128 * 64];

    // ---------------- phase 1: full h row (128 px) ----------------
    {
        f32x4 acc[4][8];
        #pragma unroll
        for (int m = 0; m < 4; ++m)
            #pragma unroll
            for (int pt = 0; pt < 8; ++pt)
                acc[m][pt] = f32x4{0.f, 0.f, 0.f, 0.f};

        #pragma unroll
        for (int s = 0; s < 18; ++s) {
            const int tap = s >> 1, trow = tap / 3, dq = tap % 3 - 1;
            const int k0 = (s & 1) * 32 + lhi * 8;
            const int grow = p + trow - 1;
            const bool rok = (unsigned)grow < (unsigned)H;
            const int cg = rok ? grow : 0;

            bf16x8 Y[8];
            #pragma unroll
            for (int pt = 0; pt < 8; ++pt) {
                int col = pt * 16 + l15 + dq;
                bool ok = rok && ((unsigned)col < (unsigned)W);
                int cl = col < 0 ? 0 : (col > 127 ? 127 : col);
                bf16x8 v = *(const bf16x8*)&yTn[((size_t)cg * W + cl) * 64 + k0];
                Y[pt] = ok ? v : (bf16x8)0;
            }
            bf16x8 Wf[4];
            #pragma unroll
            for (int m = 0; m < 4; ++m)
                Wf[m] = *(const bf16x8*)&w1f[(size_t)((s * 4 + m) * 64 + lane) * 8];

            #pragma unroll
            for (int m = 0; m < 4; ++m)
                #pragma unroll
                for (int pt = 0; pt < 8; ++pt)
                    acc[m][pt] = __builtin_amdgcn_mfma_f32_16x16x32_bf16(
                        Wf[m], Y[pt], acc[m][pt], 0, 0, 0);
        }

        // +b1, pack bf16, swizzled write into this wave's private strip
        #pragma unroll
        for (int m = 0; m < 4; ++m) {
            float4 bq = *(const float4*)&b1[m * 16 + lhi * 4];
            #pragma unroll
            for (int pt = 0; pt < 8; ++pt) {
                int px = pt * 16 + l15;
                int cb = m * 16 + lhi * 4;
                unsigned lo = (unsigned)f2bf(acc[m][pt][0] + bq.x)
                            | ((unsigned)f2bf(acc[m][pt][1] + bq.y) << 16);
                unsigned hi = (unsigned)f2bf(acc[m][pt][2] + bq.z)
                            | ((unsigned)f2bf(acc[m][pt][3] + bq.w) << 16);
                uint2 pk; pk.x = lo; pk.y = hi;
                *(uint2*)&h_my[px * 64 + (cb ^ ((px & 7) << 3))] = pk;
            }
        }
    }
    // No __syncthreads(): readback below is same-wave only (lgkmcnt ordered).

    // ---------------- phase 2: dynamic conv ----------------
    bf16x8 hA[8][2];   // B-frags: lane l15 = pixel, k = lhi*8
    #pragma unroll
    for (int pt = 0; pt < 8; ++pt)
        #pragma unroll
        for (int ks = 0; ks < 2; ++ks) {
            int px = pt * 16 + l15;
            int ko = ks * 32 + lhi * 8;
            hA[pt][ks] = *(const bf16x8*)&h_my[px * 64 + (ko ^ ((px & 7) << 3))];
        }

    const float* xn_ = x + (size_t)n * C * HW;
    float* out_ = out + (size_t)n * C * HW;

    #pragma unroll
    for (int cc = 0; cc < 4; ++cc) {
        bf16x8 wA0[2], wA1[2];
        f32x4  bq[2];
        float  xv[2][8][4];   // [buf][pt][r]

        auto loadTap = [&](int tap, int bi) {
            const int t9 = cc * 9 + tap;
            wA0[bi] = *(const bf16x8*)&w2f[(size_t)((t9 * 2 + 0) * 64 + lane) * 8];
            wA1[bi] = *(const bf16x8*)&w2f[(size_t)((t9 * 2 + 1) * 64 + lane) * 8];
            bq[bi]  = *(const f32x4*)&b2f[(size_t)(t9 * 64 + lane) * 4];
            const int ri = tap / 3, cj = tap % 3;
            const int grow = p + ri - 1;                    // wave-uniform
            const bool rok = (unsigned)grow < (unsigned)H;
            const int cr = rok ? grow : 0;
            #pragma unroll
            for (int pt = 0; pt < 8; ++pt) {
                int col = pt * 16 + l15 + cj - 1;
                bool ok = rok && ((unsigned)col < (unsigned)W);
                int cl = col < 0 ? 0 : (col > 127 ? 127 : col);
                const float* xb = xn_ + (size_t)(cc * 16 + lhi * 4) * HW
                                + (size_t)cr * W + cl;
                #pragma unroll
                for (int r = 0; r < 4; ++r) {
                    float v = xb[(size_t)r * HW];
                    xv[bi][pt][r] = ok ? v : 0.f;
                }
            }
        };

        f32x4 oacc[8];
        #pragma unroll
        for (int pt = 0; pt < 8; ++pt) oacc[pt] = f32x4{0.f, 0.f, 0.f, 0.f};

        loadTap(0, 0);
        #pragma unroll
        for (int tap = 0; tap < 9; ++tap) {
            if (tap < 8) loadTap(tap + 1, (tap + 1) & 1);
            const int bi = tap & 1;
            #pragma unroll
            for (int pt = 0; pt < 8; ++pt) {
                f32x4 kf = __builtin_amdgcn_mfma_f32_16x16x32_bf16(
                    wA0[bi], hA[pt][0], bq[bi], 0, 0, 0);
                kf = __builtin_amdgcn_mfma_f32_16x16x32_bf16(
                    wA1[bi], hA[pt][1], kf, 0, 0, 0);
                #pragma unroll
                for (int r = 0; r < 4; ++r)
                    oacc[pt][r] = fmaf(kf[r], xv[bi][pt][r], oacc[pt][r]);
            }
        }

        // coalesced stores: lane l15 = consecutive pixels
        #pragma unroll
        for (int pt = 0; pt < 8; ++pt)
            #pragma unroll
            for (int r = 0; r < 4; ++r)
                out_[(size_t)(cc * 16 + lhi * 4 + r) * HW
                     + (size_t)p * W + pt * 16 + l15] = oacc[pt][r];
    }
}

extern "C" void kernel_launch(void* const* d_in, const int* in_sizes, int n_in,
                              void* d_out, int out_size, void* d_ws, size_t ws_size,
                              hipStream_t stream)
{
    const float* x  = (const float*)d_in[0];
    const float* y  = (const float*)d_in[1];
    const float* w1 = (const float*)d_in[2];
    const float* b1 = (const float*)d_in[3];
    const float* w2 = (const float*)d_in[4];
    const float* b2 = (const float*)d_in[5];
    float* out = (float*)d_out;

    char* ws = (char*)d_ws;
    unsigned short* yT  = (unsigned short*)ws;                        // 16,777,216 B
    unsigned short* w1f = (unsigned short*)(ws + 16777216);           // 73,728 B
    unsigned short* w2f = (unsigned short*)(ws + 16777216 + 73728);   // 73,728 B
    float*          b2f = (float*)(ws + 16777216 + 147456);           // 36,864 B

    prep_weights<<<144, 256, 0, stream>>>(w1, w2, b2, w1f, w2f, b2f);
    transpose_y<<<NB * HW / 64, 256, 0, stream>>>(y, yT);
    fused_dc<<<NB * H / 4, 256, 0, stream>>>(x, yT, w1f, b1, w2f, b2f, out);
}